// Round 7
// baseline (255.297 us; speedup 1.0000x reference)
//
#include <hip/hip_runtime.h>
#include <math.h>
#include <stdint.h>

#define N_NODES 8192
#define D 7
#define K 32
#define NT 512
#define QB 8
#define CPT (N_NODES / NT)   // 16 j's per thread
#define ECAP 384             // screen-survivor capacity (per query)
#define ECAP2 160            // exact-pruned rank capacity (per query)
#define DELTA 0.125f         // f16-screen error bound (analytic ~0.06)

typedef unsigned long long u64;
typedef _Float16 h2 __attribute__((ext_vector_type(2)));

__device__ __forceinline__ float rfl(float v) {
    return __uint_as_float(__builtin_amdgcn_readfirstlane(__float_as_uint(v)));
}
__device__ __forceinline__ unsigned rflu(unsigned v) {
    return __builtin_amdgcn_readfirstlane(v);
}
__device__ __forceinline__ h2 h2u(unsigned u) {
    union { unsigned u; h2 h; } t; t.u = u; return t.h;
}
__device__ __forceinline__ unsigned pkh(float a, float b) {
    union { h2 h; unsigned u; } t;
    t.h[0] = (_Float16)a; t.h[1] = (_Float16)b; return t.u;
}

#if __has_builtin(__builtin_amdgcn_fdot2)
#define FDOT2(a, b, c) __builtin_amdgcn_fdot2((a), (b), (c), false)
#else
__device__ __forceinline__ float FDOT2(h2 a, h2 b, float c) {
    return fmaf((float)a[1], (float)b[1], fmaf((float)a[0], (float)b[0], c));
}
#endif

// exact m = sqj - 2*dot(fi, fj); identical rounding chain at every call site.
// B.w carries sq_i (not part of the dot).
__device__ __forceinline__ float dist_m(float4 b0, float4 b1, float sqj,
                                        float4 A, float4 B) {
    float dot = A.x * b0.x;
    dot = fmaf(A.y, b0.y, dot);
    dot = fmaf(A.z, b0.z, dot);
    dot = fmaf(A.w, b0.w, dot);
    dot = fmaf(B.x, b1.x, dot);
    dot = fmaf(B.y, b1.y, dot);
    dot = fmaf(B.z, b1.z, dot);
    return fmaf(-2.0f, dot, sqj);
}

// screen m via packed f16 dot2 chain — identical sequence in pass 1 and 2.
__device__ __forceinline__ float screen_m(uint4 dj, unsigned s0, unsigned s1,
                                          unsigned s2, unsigned s3) {
    return FDOT2(h2u(dj.x), h2u(s0),
           FDOT2(h2u(dj.y), h2u(s1),
           FDOT2(h2u(dj.z), h2u(s2),
           FDOT2(h2u(dj.w), h2u(s3), 0.f))));
}

// ---------------------------------------------------------------------------
// Kernel 1: out = clip(feat @ W^T, -1, 1), sq = rowsum(feat^2),
//           packed f16 row [f0..f6, sq] (16 B/node) for the dot2 screen.
// ---------------------------------------------------------------------------
__global__ __launch_bounds__(256)
void precompute_kernel(const float* __restrict__ x, const float* __restrict__ W,
                       float* __restrict__ outb, float* __restrict__ sqb,
                       uint4* __restrict__ fh)
{
    int n = blockIdx.x * 256 + threadIdx.x;
    float4 v0 = *reinterpret_cast<const float4*>(x + n * 8);
    float4 v1 = *reinterpret_cast<const float4*>(x + n * 8 + 4);
    float f[D] = {v0.x, v0.y, v0.z, v0.w, v1.x, v1.y, v1.z};
    float sq = 0.f;
#pragma unroll
    for (int c = 0; c < D; ++c) sq += f[c] * f[c];
    sqb[n] = sq;
    uint4 h;
    h.x = pkh(f[0], f[1]); h.y = pkh(f[2], f[3]);
    h.z = pkh(f[4], f[5]); h.w = pkh(f[6], sq);
    fh[n] = h;
#pragma unroll
    for (int r = 0; r < D; ++r) {
        float acc = 0.f;
#pragma unroll
        for (int c = 0; c < D; ++c) acc += f[c] * W[r * D + c];
        acc = fminf(fmaxf(acc, -1.f), 1.f);
        outb[n * D + r] = acc;
    }
}

// ---------------------------------------------------------------------------
// Kernel 2: exact top-32 (jax.lax.top_k order) + attention.
// f16 screen (unroll 4) -> exact fp32 prune at Tfin+DELTA -> tiny rank set.
// ---------------------------------------------------------------------------
__global__ __launch_bounds__(NT, 4)
void gat_kernel(const float* __restrict__ x, const float* __restrict__ aw,
                const float* __restrict__ outb, const float* __restrict__ sqb,
                const uint4* __restrict__ fh, float* __restrict__ dout)
{
    __shared__ int   ent[QB][ECAP];    // 12 KB: screen-survivor j's
    __shared__ u64   cand[QB][ECAP2];  // 10 KB: exact-pruned (dist,idx) keys
    __shared__ int   nbr[QB][K];
    __shared__ float Tsh[8][QB];
    __shared__ float Tfin[QB];
    __shared__ float exth[QB];         // exact prune threshold (LDS: runtime-q safe)
    __shared__ int   scnt[QB];
    __shared__ int   cnt2[QB];
    __shared__ float qf[QB][8];        // exact f32 query feats + sqi
    __shared__ float redv[8];
    __shared__ int   redi[8];
    __shared__ float bcv;
    __shared__ int   bci;

    const int tid  = threadIdx.x;
    const int lane = tid & 63;
    const int wave = tid >> 6;
    const int i0   = blockIdx.x * QB;

    // packed screen-query scalars (SGPR; static indexing only)
    unsigned qs0[QB], qs1[QB], qs2[QB], qs3[QB];
    float sqi[QB];
#pragma unroll
    for (int q = 0; q < QB; ++q) {
        const float* xq = x + (i0 + q) * 8;
        float4 a0 = *reinterpret_cast<const float4*>(xq);
        float4 a1 = *reinterpret_cast<const float4*>(xq + 4);
        qs0[q] = rflu(pkh(-2.f * a0.x, -2.f * a0.y));
        qs1[q] = rflu(pkh(-2.f * a0.z, -2.f * a0.w));
        qs2[q] = rflu(pkh(-2.f * a1.x, -2.f * a1.y));
        qs3[q] = rflu(pkh(-2.f * a1.z, 1.0f));
        sqi[q] = rfl(sqb[i0 + q]);
    }
    if (tid < QB) {
        const float* xq = x + (i0 + tid) * 8;
#pragma unroll
        for (int c = 0; c < D; ++c) qf[tid][c] = xq[c];
        qf[tid][7] = sqb[i0 + tid];
        scnt[tid] = 0;
        cnt2[tid] = 0;
    }

    // ---- pass 1: f16 screen, lane-min per query (unroll 4 -> 4 loads in flight)
    float lm[QB];
#pragma unroll
    for (int q = 0; q < QB; ++q) lm[q] = INFINITY;

#pragma unroll 4
    for (int c = 0; c < CPT; ++c) {
        uint4 dj = fh[c * NT + tid];
#pragma unroll
        for (int q = 0; q < QB; ++q)
            lm[q] = fminf(lm[q], screen_m(dj, qs0[q], qs1[q], qs2[q], qs3[q]));
    }

    // ---- per-wave bitonic sort of 64 lane-mins; pos 4 = 5th smallest.
    //      >= 8*5 = 40 screen values <= Tfin (incl diag -> >=39 non-diag >= 33).
#pragma unroll
    for (int q = 0; q < QB; ++q) {
        float v = lm[q];
#pragma unroll
        for (int k = 2; k <= 64; k <<= 1) {
#pragma unroll
            for (int j = k >> 1; j > 0; j >>= 1) {
                float o  = __shfl_xor(v, j);
                bool up  = ((lane & k) == 0);
                bool lo  = ((lane & j) == 0);
                v = (lo == up) ? fminf(v, o) : fmaxf(v, o);
            }
        }
        float t = __shfl(v, 4);
        if (lane == 0) Tsh[wave][q] = t;
    }
    __syncthreads();

    if (tid < QB) {
        float mx = Tsh[0][tid];
#pragma unroll
        for (int w = 1; w < 8; ++w) mx = fmaxf(mx, Tsh[w][tid]);
        Tfin[tid] = mx;
        // exact 32nd (non-diag) provably has m_e <= Tfin + DELTA; clamp region -sqi.
        exth[tid] = fmaxf(mx + DELTA, -qf[tid][7]);
    }
    __syncthreads();

    // screen-keep threshold (covers exact top-32 via +2*DELTA, clamp via +DELTA)
    float kthr[QB];
#pragma unroll
    for (int q = 0; q < QB; ++q)
        kthr[q] = fmaxf(Tfin[q] + 2.f * DELTA, -sqi[q] + DELTA);

    // ---- pass 2: f16 recompute, compact screen-survivor j's ----
#pragma unroll 4
    for (int c = 0; c < CPT; ++c) {
        int j = c * NT + tid;
        uint4 dj = fh[j];
#pragma unroll
        for (int q = 0; q < QB; ++q) {
            float m = screen_m(dj, qs0[q], qs1[q], qs2[q], qs3[q]);
            if (m <= kthr[q] && j != i0 + q) {
                int p = atomicAdd(&scnt[q], 1);
                if (p < ECAP) ent[q][p] = j;
            }
        }
    }
    __syncthreads();

    // ---- dense exact fp32 phase with PRUNE at exth: rank set shrinks 3-8x ----
    const float4* xb = reinterpret_cast<const float4*>(x);
#pragma unroll 1
    for (int q = 0; q < QB; ++q) {
        int n = scnt[q];
        if (n > ECAP) n = ECAP;
        float4 A  = *reinterpret_cast<const float4*>(&qf[q][0]);
        float4 Bv = *reinterpret_cast<const float4*>(&qf[q][4]);  // .w = sqi
        float thr = exth[q];
        for (int t = tid; t < n; t += NT) {
            int j = ent[q][t];
            float4 b0 = xb[j * 2];
            float4 b1 = xb[j * 2 + 1];
            float m   = dist_m(b0, b1, sqb[j], A, Bv);
            if (m <= thr) {
                float d2c = fmaxf(Bv.w + m, 0.f);
                u64 key = ((u64)__float_as_uint(d2c) << 32) | (unsigned)j;
                int p = atomicAdd(&cnt2[q], 1);
                if (p < ECAP2) cand[q][p] = key;
            }
        }
    }
    __syncthreads();

    // ---- selection: wave w -> query w, exact rank-by-counting (small M) ----
    {
        const int q = wave;
        const int M = cnt2[q];
        if (scnt[q] <= ECAP && M >= K && M <= ECAP2) {
            for (int p = lane; p < M; p += 64) {
                u64 my = cand[q][p];
                int rank = 0;
                for (int m = 0; m < M; ++m)
                    rank += (cand[q][m] < my) ? 1 : 0;
                if (rank < K) nbr[q][rank] = (int)(my & 0xffffffffu);
            }
        }
    }
    __syncthreads();

    // ---- exact fallback (cold): screen/prune failed for some query ----
#pragma unroll 1
    for (int q = 0; q < QB; ++q) {
        int s = scnt[q];                   // block-uniform reads
        int M = cnt2[q];
        if (s > ECAP || M < K || M > ECAP2) {
            const int iq = i0 + q;
            const float* xq = x + iq * 8;
            float4 A  = *reinterpret_cast<const float4*>(xq);
            float4 Bv = *reinterpret_cast<const float4*>(xq + 4);
            Bv.w = sqb[iq];
            float lastv = -1.0f; int lasti = -1;
#pragma unroll 1
            for (int it = 0; it < K; ++it) {
                float best = INFINITY; int bidx = 0x7fffffff;
#pragma unroll 1
                for (int c = 0; c < CPT; ++c) {
                    int j = c * NT + tid;
                    float4 b0 = xb[j * 2];
                    float4 b1 = xb[j * 2 + 1];
                    float m = dist_m(b0, b1, sqb[j], A, Bv);
                    float d2c = fmaxf(Bv.w + m, 0.f);
                    if (j == iq) continue;
                    bool gt = (d2c > lastv) || (d2c == lastv && j > lasti);
                    if (gt && (d2c < best || (d2c == best && j < bidx))) {
                        best = d2c; bidx = j;
                    }
                }
#pragma unroll
                for (int off = 32; off > 0; off >>= 1) {
                    float ov = __shfl_down(best, off);
                    int   oi = __shfl_down(bidx, off);
                    if (ov < best || (ov == best && oi < bidx)) { best = ov; bidx = oi; }
                }
                if (lane == 0) { redv[wave] = best; redi[wave] = bidx; }
                __syncthreads();
                if (tid == 0) {
                    float bv = redv[0]; int bi = redi[0];
#pragma unroll
                    for (int w = 1; w < 8; ++w)
                        if (redv[w] < bv || (redv[w] == bv && redi[w] < bi)) {
                            bv = redv[w]; bi = redi[w];
                        }
                    bcv = bv; bci = bi;
                    nbr[q][it] = bi;
                }
                __syncthreads();
                lastv = bcv; lasti = bci;
            }
        }
    }
    __syncthreads();

    // ---- attention epilogue: wave w -> query w, lanes 0..31 ----
    {
        const int q  = wave;
        const int iq = i0 + q;
        if (lane < K) {
            int nk = nbr[q][lane];
            float s = 0.f;
#pragma unroll
            for (int c = 0; c < D; ++c) s += outb[iq * D + c] * aw[c];
            float xp[D + 1];
#pragma unroll
            for (int c = 0; c < D; ++c) {
                float on = outb[nk * D + c];
                xp[c] = on;
                s += on * aw[D + c];
            }
            xp[D] = x[nk * 8 + 7];

            float m = s;
#pragma unroll
            for (int off = 16; off > 0; off >>= 1) m = fmaxf(m, __shfl_xor(m, off, 32));
            float e = expf(s - m);
            float sum = e;
#pragma unroll
            for (int off = 16; off > 0; off >>= 1) sum += __shfl_xor(sum, off, 32);
            float att = e / sum;

            float agg[D + 1];
#pragma unroll
            for (int dd = 0; dd < D + 1; ++dd) {
                float v = att * xp[dd];
#pragma unroll
                for (int off = 16; off > 0; off >>= 1) v += __shfl_xor(v, off, 32);
                agg[dd] = v;
            }

            if (lane < D) {
                float o = outb[iq * D + lane];
                dout[iq * 15 + lane] = o;
                dout[N_NODES * 15 + iq * 15 + lane] = o;
            }
            if (lane < D + 1) {
                float av_ = agg[0];
#pragma unroll
                for (int dd = 1; dd < D + 1; ++dd) av_ = (lane == dd) ? agg[dd] : av_;
                dout[iq * 15 + D + lane] = av_;
                dout[N_NODES * 15 + iq * 15 + D + lane] = av_;
            }
            if (iq == N_NODES - 1) dout[2 * N_NODES * 15 + lane] = att;
        }
    }
}

extern "C" void kernel_launch(void* const* d_in, const int* in_sizes, int n_in,
                              void* d_out, int out_size, void* d_ws, size_t ws_size,
                              hipStream_t stream) {
    (void)in_sizes; (void)n_in; (void)out_size; (void)ws_size;
    const float* x = (const float*)d_in[0];
    const float* W = (const float*)d_in[1];
    const float* a = (const float*)d_in[2];
    float* out  = (float*)d_out;
    float* outb = (float*)d_ws;                       // 8192*7 f32
    float* sqb  = outb + N_NODES * D;                 // 8192 f32
    uint4* fh   = (uint4*)(sqb + N_NODES);            // 8192 * 16 B (16B-aligned)

    hipLaunchKernelGGL(precompute_kernel, dim3(N_NODES / 256), dim3(256),
                       0, stream, x, W, outb, sqb, fh);
    hipLaunchKernelGGL(gat_kernel, dim3(N_NODES / QB), dim3(NT),
                       0, stream, x, a, outb, sqb, fh, out);
}

// Round 8
// 116.427 us; speedup vs baseline: 2.1928x; 2.1928x over previous
//
#include <hip/hip_runtime.h>
#include <math.h>
#include <stdint.h>

#define N_NODES 8192
#define D 7
#define K 32
#define NT 512
#define QB 8
#define CPT (N_NODES / NT)   // 16 j's per thread
#define ECAP 384             // screen-survivor capacity (per query)
#define ECAP2 256            // exact-pruned rank capacity (per query)
#define DELTA 0.125f         // f16-screen error bound (analytic ~0.09 worst-case)

typedef unsigned long long u64;
typedef _Float16 h2 __attribute__((ext_vector_type(2)));

__device__ __forceinline__ float rfl(float v) {
    return __uint_as_float(__builtin_amdgcn_readfirstlane(__float_as_uint(v)));
}
__device__ __forceinline__ unsigned rflu(unsigned v) {
    return __builtin_amdgcn_readfirstlane(v);
}
__device__ __forceinline__ h2 h2u(unsigned u) {
    union { unsigned u; h2 h; } t; t.u = u; return t.h;
}
__device__ __forceinline__ unsigned pkh(float a, float b) {
    union { h2 h; unsigned u; } t;
    t.h[0] = (_Float16)a; t.h[1] = (_Float16)b; return t.u;
}
// order-preserving float<->uint (total order, handles negatives)
__device__ __forceinline__ unsigned ordu(float f) {
    unsigned u = __float_as_uint(f);
    return (u & 0x80000000u) ? ~u : (u | 0x80000000u);
}
__device__ __forceinline__ float unordu(unsigned o) {
    unsigned u = (o & 0x80000000u) ? (o & 0x7fffffffu) : ~o;
    return __uint_as_float(u);
}

#if __has_builtin(__builtin_amdgcn_fdot2)
#define FDOT2(a, b, c) __builtin_amdgcn_fdot2((a), (b), (c), false)
#else
__device__ __forceinline__ float FDOT2(h2 a, h2 b, float c) {
    return fmaf((float)a[1], (float)b[1], fmaf((float)a[0], (float)b[0], c));
}
#endif

// exact m = sqj - 2*dot(fi, fj); identical rounding chain at every call site.
// B.w carries sq_i (not part of the dot).
__device__ __forceinline__ float dist_m(float4 b0, float4 b1, float sqj,
                                        float4 A, float4 B) {
    float dot = A.x * b0.x;
    dot = fmaf(A.y, b0.y, dot);
    dot = fmaf(A.z, b0.z, dot);
    dot = fmaf(A.w, b0.w, dot);
    dot = fmaf(B.x, b1.x, dot);
    dot = fmaf(B.y, b1.y, dot);
    dot = fmaf(B.z, b1.z, dot);
    return fmaf(-2.0f, dot, sqj);
}

// screen m via packed f16 dot2 chain — identical sequence in pass 1 and 2.
__device__ __forceinline__ float screen_m(uint4 dj, unsigned s0, unsigned s1,
                                          unsigned s2, unsigned s3) {
    return FDOT2(h2u(dj.x), h2u(s0),
           FDOT2(h2u(dj.y), h2u(s1),
           FDOT2(h2u(dj.z), h2u(s2),
           FDOT2(h2u(dj.w), h2u(s3), 0.f))));
}

// ---------------------------------------------------------------------------
// Kernel 1: out = clip(feat @ W^T, -1, 1), sq = rowsum(feat^2),
//           packed f16 row [f0..f6, sq] (16 B/node) for the dot2 screen.
// ---------------------------------------------------------------------------
__global__ __launch_bounds__(256)
void precompute_kernel(const float* __restrict__ x, const float* __restrict__ W,
                       float* __restrict__ outb, float* __restrict__ sqb,
                       uint4* __restrict__ fh)
{
    int n = blockIdx.x * 256 + threadIdx.x;
    float4 v0 = *reinterpret_cast<const float4*>(x + n * 8);
    float4 v1 = *reinterpret_cast<const float4*>(x + n * 8 + 4);
    float f[D] = {v0.x, v0.y, v0.z, v0.w, v1.x, v1.y, v1.z};
    float sq = 0.f;
#pragma unroll
    for (int c = 0; c < D; ++c) sq += f[c] * f[c];
    sqb[n] = sq;
    uint4 h;
    h.x = pkh(f[0], f[1]); h.y = pkh(f[2], f[3]);
    h.z = pkh(f[4], f[5]); h.w = pkh(f[6], sq);
    fh[n] = h;
#pragma unroll
    for (int r = 0; r < D; ++r) {
        float acc = 0.f;
#pragma unroll
        for (int c = 0; c < D; ++c) acc += f[c] * W[r * D + c];
        acc = fminf(fmaxf(acc, -1.f), 1.f);
        outb[n * D + r] = acc;
    }
}

// ---------------------------------------------------------------------------
// Kernel 2: exact top-32 (jax.lax.top_k order) + attention.
// f16 screen -> EXACT 33rd-of-512 lane-min threshold -> exact fp32 prune ->
// small rank set. Provably exact at every step; cold fallback retained.
// ---------------------------------------------------------------------------
__global__ __launch_bounds__(NT, 4)
void gat_kernel(const float* __restrict__ x, const float* __restrict__ aw,
                const float* __restrict__ outb, const float* __restrict__ sqb,
                const uint4* __restrict__ fh, float* __restrict__ dout)
{
    __shared__ int      ent[QB][ECAP];    // 12 KB: screen-survivor j's
    __shared__ u64      cand[QB][ECAP2];  // 16 KB: exact keys (aliases Lsort)
    __shared__ int      nbr[QB][K];
    __shared__ unsigned selT[QB];
    __shared__ float    exthL[QB];        // exact prune threshold (runtime-q safe)
    __shared__ int      scnt[QB];
    __shared__ int      cnt2[QB];
    __shared__ float    qf[QB][8];        // exact f32 query feats + sqi
    __shared__ float    redv[8];
    __shared__ int      redi[8];
    __shared__ float    bcv;
    __shared__ int      bci;

    float* Lsort = (float*)cand;          // [QB][8][64] sorted lane-mins, 16 KB

    const int tid  = threadIdx.x;
    const int lane = tid & 63;
    const int wave = tid >> 6;
    const int i0   = blockIdx.x * QB;

    // packed screen-query scalars (SGPR; static indexing only)
    unsigned qs0[QB], qs1[QB], qs2[QB], qs3[QB];
    float sqi[QB];
#pragma unroll
    for (int q = 0; q < QB; ++q) {
        const float* xq = x + (i0 + q) * 8;
        float4 a0 = *reinterpret_cast<const float4*>(xq);
        float4 a1 = *reinterpret_cast<const float4*>(xq + 4);
        qs0[q] = rflu(pkh(-2.f * a0.x, -2.f * a0.y));
        qs1[q] = rflu(pkh(-2.f * a0.z, -2.f * a0.w));
        qs2[q] = rflu(pkh(-2.f * a1.x, -2.f * a1.y));
        qs3[q] = rflu(pkh(-2.f * a1.z, 1.0f));
        sqi[q] = rfl(sqb[i0 + q]);
    }
    if (tid < QB) {
        const float* xq = x + (i0 + tid) * 8;
#pragma unroll
        for (int c = 0; c < D; ++c) qf[tid][c] = xq[c];
        qf[tid][7] = sqb[i0 + tid];
        scnt[tid] = 0;
        cnt2[tid] = 0;
        selT[tid] = 0xFFFFFFFFu;
    }

    // ---- pass 1: f16 screen, lane-min per query (4 loads in flight) ----
    float lm[QB];
#pragma unroll
    for (int q = 0; q < QB; ++q) lm[q] = INFINITY;

#pragma unroll 4
    for (int c = 0; c < CPT; ++c) {
        uint4 dj = fh[c * NT + tid];
#pragma unroll
        for (int q = 0; q < QB; ++q)
            lm[q] = fminf(lm[q], screen_m(dj, qs0[q], qs1[q], qs2[q], qs3[q]));
    }

    // ---- per-wave ascending bitonic sort of 64 lane-mins -> Lsort ----
#pragma unroll
    for (int q = 0; q < QB; ++q) {
        float v = lm[q];
#pragma unroll
        for (int k = 2; k <= 64; k <<= 1) {
#pragma unroll
            for (int j = k >> 1; j > 0; j >>= 1) {
                float o  = __shfl_xor(v, j);
                bool up  = ((lane & k) == 0);
                bool lo  = ((lane & j) == 0);
                v = (lo == up) ? fminf(v, o) : fmaxf(v, o);
            }
        }
        Lsort[(q * 8 + wave) * 64 + lane] = v;
    }
    __syncthreads();

    // ---- EXACT 33rd-smallest of the 512 lane-mins (per query) ----
    // Candidates: first 33 sorted values of each wave (33rd global must be one).
    // rank(v) = sum over waves of count(<= v) via binary search; smallest v
    // with rank >= 33 is the 33rd smallest -> atomicMin on ordered bits.
    for (int t = tid; t < QB * 264; t += NT) {
        int q = t / 264;
        int r = t - q * 264;
        int w = r / 33;
        int p = r - w * 33;
        float v = Lsort[(q * 8 + w) * 64 + p];
        int rank = 0;
#pragma unroll
        for (int w2 = 0; w2 < 8; ++w2) {
            const float* A = &Lsort[(q * 8 + w2) * 64];
            int lo = 0, hi = 64;
            while (lo < hi) {
                int mid = (lo + hi) >> 1;
                if (A[mid] <= v) lo = mid + 1; else hi = mid;
            }
            rank += lo;
        }
        if (rank >= 33) atomicMin(&selT[q], ordu(v));
    }
    __syncthreads();

    // thresholds: >=33 lane-mins (distinct j) <= Tsel => >=32 non-diag;
    // exact 32nd <= Tsel+DELTA; screen of any exact-top-32 <= Tsel+2*DELTA.
    float kthr[QB];
#pragma unroll
    for (int q = 0; q < QB; ++q) {
        float Ts = unordu(selT[q]);
        kthr[q] = fmaxf(Ts + 2.f * DELTA, -sqi[q] + DELTA);
    }
    if (tid < QB) {
        float Ts = unordu(selT[tid]);
        exthL[tid] = fmaxf(Ts + DELTA, -qf[tid][7]);
    }

    // ---- pass 2: f16 recompute, compact screen-survivor j's ----
#pragma unroll 4
    for (int c = 0; c < CPT; ++c) {
        int j = c * NT + tid;
        uint4 dj = fh[j];
#pragma unroll
        for (int q = 0; q < QB; ++q) {
            float m = screen_m(dj, qs0[q], qs1[q], qs2[q], qs3[q]);
            if (m <= kthr[q] && j != i0 + q) {
                int p = atomicAdd(&scnt[q], 1);
                if (p < ECAP) ent[q][p] = j;
            }
        }
    }
    __syncthreads();   // also fences Lsort reads before cand overwrite

    // ---- dense exact fp32 phase with prune at exthL ----
    const float4* xb = reinterpret_cast<const float4*>(x);
#pragma unroll 1
    for (int q = 0; q < QB; ++q) {
        int n = scnt[q];
        if (n > ECAP) n = ECAP;
        float4 A  = *reinterpret_cast<const float4*>(&qf[q][0]);
        float4 Bv = *reinterpret_cast<const float4*>(&qf[q][4]);  // .w = sqi
        float thr = exthL[q];
        for (int t = tid; t < n; t += NT) {
            int j = ent[q][t];
            float4 b0 = xb[j * 2];
            float4 b1 = xb[j * 2 + 1];
            float m   = dist_m(b0, b1, sqb[j], A, Bv);
            if (m <= thr) {
                float d2c = fmaxf(Bv.w + m, 0.f);
                u64 key = ((u64)__float_as_uint(d2c) << 32) | (unsigned)j;
                int p = atomicAdd(&cnt2[q], 1);
                if (p < ECAP2) cand[q][p] = key;
            }
        }
    }
    __syncthreads();

    // ---- selection: wave w -> query w, exact rank-by-counting (small M) ----
    {
        const int q = wave;
        const int M = cnt2[q];
        if (scnt[q] <= ECAP && M >= K && M <= ECAP2) {
            for (int p = lane; p < M; p += 64) {
                u64 my = cand[q][p];
                int rank = 0;
                for (int m = 0; m < M; ++m)
                    rank += (cand[q][m] < my) ? 1 : 0;
                if (rank < K) nbr[q][rank] = (int)(my & 0xffffffffu);
            }
        }
    }
    __syncthreads();

    // ---- exact fallback (cold, ~never): full sequential extraction ----
#pragma unroll 1
    for (int q = 0; q < QB; ++q) {
        int s = scnt[q];                   // block-uniform reads
        int M = cnt2[q];
        if (s > ECAP || M < K || M > ECAP2) {
            const int iq = i0 + q;
            const float* xq = x + iq * 8;
            float4 A  = *reinterpret_cast<const float4*>(xq);
            float4 Bv = *reinterpret_cast<const float4*>(xq + 4);
            Bv.w = sqb[iq];
            float lastv = -1.0f; int lasti = -1;
#pragma unroll 1
            for (int it = 0; it < K; ++it) {
                float best = INFINITY; int bidx = 0x7fffffff;
#pragma unroll 1
                for (int c = 0; c < CPT; ++c) {
                    int j = c * NT + tid;
                    float4 b0 = xb[j * 2];
                    float4 b1 = xb[j * 2 + 1];
                    float m = dist_m(b0, b1, sqb[j], A, Bv);
                    float d2c = fmaxf(Bv.w + m, 0.f);
                    if (j == iq) continue;
                    bool gt = (d2c > lastv) || (d2c == lastv && j > lasti);
                    if (gt && (d2c < best || (d2c == best && j < bidx))) {
                        best = d2c; bidx = j;
                    }
                }
#pragma unroll
                for (int off = 32; off > 0; off >>= 1) {
                    float ov = __shfl_down(best, off);
                    int   oi = __shfl_down(bidx, off);
                    if (ov < best || (ov == best && oi < bidx)) { best = ov; bidx = oi; }
                }
                if (lane == 0) { redv[wave] = best; redi[wave] = bidx; }
                __syncthreads();
                if (tid == 0) {
                    float bv = redv[0]; int bi = redi[0];
#pragma unroll
                    for (int w = 1; w < 8; ++w)
                        if (redv[w] < bv || (redv[w] == bv && redi[w] < bi)) {
                            bv = redv[w]; bi = redi[w];
                        }
                    bcv = bv; bci = bi;
                    nbr[q][it] = bi;
                }
                __syncthreads();
                lastv = bcv; lasti = bci;
            }
        }
    }
    __syncthreads();

    // ---- attention epilogue: wave w -> query w, lanes 0..31 ----
    {
        const int q  = wave;
        const int iq = i0 + q;
        if (lane < K) {
            int nk = nbr[q][lane];
            float s = 0.f;
#pragma unroll
            for (int c = 0; c < D; ++c) s += outb[iq * D + c] * aw[c];
            float xp[D + 1];
#pragma unroll
            for (int c = 0; c < D; ++c) {
                float on = outb[nk * D + c];
                xp[c] = on;
                s += on * aw[D + c];
            }
            xp[D] = x[nk * 8 + 7];

            float m = s;
#pragma unroll
            for (int off = 16; off > 0; off >>= 1) m = fmaxf(m, __shfl_xor(m, off, 32));
            float e = expf(s - m);
            float sum = e;
#pragma unroll
            for (int off = 16; off > 0; off >>= 1) sum += __shfl_xor(sum, off, 32);
            float att = e / sum;

            float agg[D + 1];
#pragma unroll
            for (int dd = 0; dd < D + 1; ++dd) {
                float v = att * xp[dd];
#pragma unroll
                for (int off = 16; off > 0; off >>= 1) v += __shfl_xor(v, off, 32);
                agg[dd] = v;
            }

            if (lane < D) {
                float o = outb[iq * D + lane];
                dout[iq * 15 + lane] = o;
                dout[N_NODES * 15 + iq * 15 + lane] = o;
            }
            if (lane < D + 1) {
                float av_ = agg[0];
#pragma unroll
                for (int dd = 1; dd < D + 1; ++dd) av_ = (lane == dd) ? agg[dd] : av_;
                dout[iq * 15 + D + lane] = av_;
                dout[N_NODES * 15 + iq * 15 + D + lane] = av_;
            }
            if (iq == N_NODES - 1) dout[2 * N_NODES * 15 + lane] = att;
        }
    }
}

extern "C" void kernel_launch(void* const* d_in, const int* in_sizes, int n_in,
                              void* d_out, int out_size, void* d_ws, size_t ws_size,
                              hipStream_t stream) {
    (void)in_sizes; (void)n_in; (void)out_size; (void)ws_size;
    const float* x = (const float*)d_in[0];
    const float* W = (const float*)d_in[1];
    const float* a = (const float*)d_in[2];
    float* out  = (float*)d_out;
    float* outb = (float*)d_ws;                       // 8192*7 f32
    float* sqb  = outb + N_NODES * D;                 // 8192 f32
    uint4* fh   = (uint4*)(sqb + N_NODES);            // 8192 * 16 B (16B-aligned)

    hipLaunchKernelGGL(precompute_kernel, dim3(N_NODES / 256), dim3(256),
                       0, stream, x, W, outb, sqb, fh);
    hipLaunchKernelGGL(gat_kernel, dim3(N_NODES / QB), dim3(NT),
                       0, stream, x, a, outb, sqb, fh, out);
}

// Round 9
// 71.376 us; speedup vs baseline: 3.5768x; 1.6312x over previous
//
#include <hip/hip_runtime.h>
#include <math.h>
#include <stdint.h>

#define N_NODES 8192
#define D 7
#define K 32
#define NT 512
#define QB 8
#define CPT (N_NODES / NT)   // 16 j's per thread
#define ECAP 384             // screen-survivor capacity (per query)
#define ECAP2 256            // exact-pruned rank capacity (per query)
#define DELTA 0.25f          // f16-screen error bound (worst-case analytic ~0.15)

typedef unsigned long long u64;
typedef _Float16 h2 __attribute__((ext_vector_type(2)));

__device__ __forceinline__ float rfl(float v) {
    return __uint_as_float(__builtin_amdgcn_readfirstlane(__float_as_uint(v)));
}
__device__ __forceinline__ unsigned rflu(unsigned v) {
    return __builtin_amdgcn_readfirstlane(v);
}
__device__ __forceinline__ h2 h2u(unsigned u) {
    union { unsigned u; h2 h; } t; t.u = u; return t.h;
}
__device__ __forceinline__ unsigned pkh(float a, float b) {
    union { h2 h; unsigned u; } t;
    t.h[0] = (_Float16)a; t.h[1] = (_Float16)b; return t.u;
}
// order-preserving float<->uint (total order, handles negatives)
__device__ __forceinline__ unsigned ordu(float f) {
    unsigned u = __float_as_uint(f);
    return (u & 0x80000000u) ? ~u : (u | 0x80000000u);
}
__device__ __forceinline__ float unordu(unsigned o) {
    unsigned u = (o & 0x80000000u) ? (o & 0x7fffffffu) : ~o;
    return __uint_as_float(u);
}

#if __has_builtin(__builtin_amdgcn_fdot2)
#define FDOT2(a, b, c) __builtin_amdgcn_fdot2((a), (b), (c), false)
#else
__device__ __forceinline__ float FDOT2(h2 a, h2 b, float c) {
    return fmaf((float)a[1], (float)b[1], fmaf((float)a[0], (float)b[0], c));
}
#endif

// exact m = sqj - 2*dot(fi, fj); identical rounding chain at every call site.
// B.w carries sq_i (not part of the dot).
__device__ __forceinline__ float dist_m(float4 b0, float4 b1, float sqj,
                                        float4 A, float4 B) {
    float dot = A.x * b0.x;
    dot = fmaf(A.y, b0.y, dot);
    dot = fmaf(A.z, b0.z, dot);
    dot = fmaf(A.w, b0.w, dot);
    dot = fmaf(B.x, b1.x, dot);
    dot = fmaf(B.y, b1.y, dot);
    dot = fmaf(B.z, b1.z, dot);
    return fmaf(-2.0f, dot, sqj);
}

// screen m via packed f16 dot2 chain — identical sequence in pass 1 and 2.
__device__ __forceinline__ float screen_m(uint4 dj, unsigned s0, unsigned s1,
                                          unsigned s2, unsigned s3) {
    return FDOT2(h2u(dj.x), h2u(s0),
           FDOT2(h2u(dj.y), h2u(s1),
           FDOT2(h2u(dj.z), h2u(s2),
           FDOT2(h2u(dj.w), h2u(s3), 0.f))));
}

// ---------------------------------------------------------------------------
// Kernel 1: out = clip(feat @ W^T, -1, 1), sq = rowsum(feat^2),
//           packed f16 row [f0..f6, sq] (16 B/node) for the dot2 screen.
// ---------------------------------------------------------------------------
__global__ __launch_bounds__(256)
void precompute_kernel(const float* __restrict__ x, const float* __restrict__ W,
                       float* __restrict__ outb, float* __restrict__ sqb,
                       uint4* __restrict__ fh)
{
    int n = blockIdx.x * 256 + threadIdx.x;
    float4 v0 = *reinterpret_cast<const float4*>(x + n * 8);
    float4 v1 = *reinterpret_cast<const float4*>(x + n * 8 + 4);
    float f[D] = {v0.x, v0.y, v0.z, v0.w, v1.x, v1.y, v1.z};
    float sq = 0.f;
#pragma unroll
    for (int c = 0; c < D; ++c) sq += f[c] * f[c];
    sqb[n] = sq;
    uint4 h;
    h.x = pkh(f[0], f[1]); h.y = pkh(f[2], f[3]);
    h.z = pkh(f[4], f[5]); h.w = pkh(f[6], sq);
    fh[n] = h;
#pragma unroll
    for (int r = 0; r < D; ++r) {
        float acc = 0.f;
#pragma unroll
        for (int c = 0; c < D; ++c) acc += f[c] * W[r * D + c];
        acc = fminf(fmaxf(acc, -1.f), 1.f);
        outb[n * D + r] = acc;
    }
}

// ---------------------------------------------------------------------------
// Kernel 2: exact top-32 (jax.lax.top_k order) + attention.
// f16 screen -> EXACT 33rd-of-512 lane-min threshold via wave-uniform
// ballot-bisection (no sort, no LDS in loop) -> exact fp32 prune -> tiny rank.
// ---------------------------------------------------------------------------
__global__ __launch_bounds__(NT, 4)
void gat_kernel(const float* __restrict__ x, const float* __restrict__ aw,
                const float* __restrict__ outb, const float* __restrict__ sqb,
                const uint4* __restrict__ fh, float* __restrict__ dout)
{
    __shared__ u64      cand[QB][ECAP2];     // 16 KB, aliases Lmin
    __shared__ unsigned short ent[QB][ECAP]; // 6 KB: screen-survivor j's
    __shared__ int      nbr[QB][K];
    __shared__ unsigned selT[QB];
    __shared__ float    exthL[QB];
    __shared__ int      scnt[QB];
    __shared__ int      cnt2[QB];
    __shared__ float    qf[QB][8];           // exact f32 query feats + sqi
    __shared__ float    redv[8];
    __shared__ int      redi[8];
    __shared__ float    bcv;
    __shared__ int      bci;

    float* Lmin = (float*)cand;              // [QB][NT] raw lane-mins (16 KB)

    const int tid  = threadIdx.x;
    const int lane = tid & 63;
    const int wave = tid >> 6;
    const int i0   = blockIdx.x * QB;

    // packed screen-query scalars (SGPR; static indexing only)
    unsigned qs0[QB], qs1[QB], qs2[QB], qs3[QB];
    float sqi[QB];
#pragma unroll
    for (int q = 0; q < QB; ++q) {
        const float* xq = x + (i0 + q) * 8;
        float4 a0 = *reinterpret_cast<const float4*>(xq);
        float4 a1 = *reinterpret_cast<const float4*>(xq + 4);
        qs0[q] = rflu(pkh(-2.f * a0.x, -2.f * a0.y));
        qs1[q] = rflu(pkh(-2.f * a0.z, -2.f * a0.w));
        qs2[q] = rflu(pkh(-2.f * a1.x, -2.f * a1.y));
        qs3[q] = rflu(pkh(-2.f * a1.z, 1.0f));
        sqi[q] = rfl(sqb[i0 + q]);
    }
    if (tid < QB) {
        const float* xq = x + (i0 + tid) * 8;
#pragma unroll
        for (int c = 0; c < D; ++c) qf[tid][c] = xq[c];
        qf[tid][7] = sqb[i0 + tid];
        scnt[tid] = 0;
        cnt2[tid] = 0;
    }

    // ---- pass 1: f16 screen, lane-min per query (4 loads in flight) ----
    float lm[QB];
#pragma unroll
    for (int q = 0; q < QB; ++q) lm[q] = INFINITY;

#pragma unroll 4
    for (int c = 0; c < CPT; ++c) {
        uint4 dj = fh[c * NT + tid];
#pragma unroll
        for (int q = 0; q < QB; ++q)
            lm[q] = fminf(lm[q], screen_m(dj, qs0[q], qs1[q], qs2[q], qs3[q]));
    }

    // raw lane-mins -> LDS (conflict-free: consecutive tid, consecutive floats)
#pragma unroll
    for (int q = 0; q < QB; ++q) Lmin[q * NT + tid] = lm[q];
    __syncthreads();

    // ---- EXACT 33rd-smallest of 512 lane-mins: wave w -> query w.
    //      Wave-uniform bisection on order-preserving uint space; count via
    //      ballot+popc on 8 register values per lane. 32 iterations, no LDS.
    {
        const int q = wave;
        unsigned ov0 = ordu(Lmin[q * NT +   0 + lane]);
        unsigned ov1 = ordu(Lmin[q * NT +  64 + lane]);
        unsigned ov2 = ordu(Lmin[q * NT + 128 + lane]);
        unsigned ov3 = ordu(Lmin[q * NT + 192 + lane]);
        unsigned ov4 = ordu(Lmin[q * NT + 256 + lane]);
        unsigned ov5 = ordu(Lmin[q * NT + 320 + lane]);
        unsigned ov6 = ordu(Lmin[q * NT + 384 + lane]);
        unsigned ov7 = ordu(Lmin[q * NT + 448 + lane]);
        unsigned lo = 0u, hi = 0xFFFFFFFFu;
        while (lo < hi) {                      // uniform: lo/hi scalar
            unsigned mid = lo + ((hi - lo) >> 1);
            int cnt = __popcll(__ballot(ov0 <= mid))
                    + __popcll(__ballot(ov1 <= mid))
                    + __popcll(__ballot(ov2 <= mid))
                    + __popcll(__ballot(ov3 <= mid))
                    + __popcll(__ballot(ov4 <= mid))
                    + __popcll(__ballot(ov5 <= mid))
                    + __popcll(__ballot(ov6 <= mid))
                    + __popcll(__ballot(ov7 <= mid));
            if (cnt >= 33) hi = mid; else lo = mid + 1;
        }
        if (lane == 0) selT[q] = lo;
    }
    __syncthreads();

    // thresholds: >=33 lane-mins (distinct j) <= Tsel => >=32 non-diag screen
    // values <= Tsel => exact 32nd <= Tsel+DELTA; screen of any exact-top-32
    // member <= Tsel+2*DELTA. Clamp-to-zero region handled via -sqi terms.
    float kthr[QB];
#pragma unroll
    for (int q = 0; q < QB; ++q) {
        float Ts = unordu(selT[q]);
        kthr[q] = fmaxf(Ts + 2.f * DELTA, -sqi[q] + DELTA);
    }
    if (tid < QB) {
        float Ts = unordu(selT[tid]);
        exthL[tid] = fmaxf(Ts + DELTA, -qf[tid][7]);
    }

    // ---- pass 2: f16 recompute, compact screen-survivor j's ----
#pragma unroll 4
    for (int c = 0; c < CPT; ++c) {
        int j = c * NT + tid;
        uint4 dj = fh[j];
#pragma unroll
        for (int q = 0; q < QB; ++q) {
            float m = screen_m(dj, qs0[q], qs1[q], qs2[q], qs3[q]);
            if (m <= kthr[q] && j != i0 + q) {
                int p = atomicAdd(&scnt[q], 1);
                if (p < ECAP) ent[q][p] = (unsigned short)j;
            }
        }
    }
    __syncthreads();   // Lmin reads done; cand may now be overwritten

    // ---- dense exact fp32 phase with prune at exthL ----
    const float4* xb = reinterpret_cast<const float4*>(x);
#pragma unroll 1
    for (int q = 0; q < QB; ++q) {
        int n = scnt[q];
        if (n > ECAP) n = ECAP;
        float4 A  = *reinterpret_cast<const float4*>(&qf[q][0]);
        float4 Bv = *reinterpret_cast<const float4*>(&qf[q][4]);  // .w = sqi
        float thr = exthL[q];
        for (int t = tid; t < n; t += NT) {
            int j = ent[q][t];
            float4 b0 = xb[j * 2];
            float4 b1 = xb[j * 2 + 1];
            float m   = dist_m(b0, b1, sqb[j], A, Bv);
            if (m <= thr) {
                float d2c = fmaxf(Bv.w + m, 0.f);
                u64 key = ((u64)__float_as_uint(d2c) << 32) | (unsigned)j;
                int p = atomicAdd(&cnt2[q], 1);
                if (p < ECAP2) cand[q][p] = key;
            }
        }
    }
    __syncthreads();

    // ---- selection: wave w -> query w, exact rank-by-counting (small M) ----
    {
        const int q = wave;
        const int M = cnt2[q];
        if (scnt[q] <= ECAP && M >= K && M <= ECAP2) {
            for (int p = lane; p < M; p += 64) {
                u64 my = cand[q][p];
                int rank = 0;
                for (int m = 0; m < M; ++m)
                    rank += (cand[q][m] < my) ? 1 : 0;
                if (rank < K) nbr[q][rank] = (int)(my & 0xffffffffu);
            }
        }
    }
    __syncthreads();

    // ---- exact fallback (cold, ~never): full sequential extraction ----
#pragma unroll 1
    for (int q = 0; q < QB; ++q) {
        int s = scnt[q];                   // block-uniform reads
        int M = cnt2[q];
        if (s > ECAP || M < K || M > ECAP2) {
            const int iq = i0 + q;
            const float* xq = x + iq * 8;
            float4 A  = *reinterpret_cast<const float4*>(xq);
            float4 Bv = *reinterpret_cast<const float4*>(xq + 4);
            Bv.w = sqb[iq];
            float lastv = -1.0f; int lasti = -1;
#pragma unroll 1
            for (int it = 0; it < K; ++it) {
                float best = INFINITY; int bidx = 0x7fffffff;
#pragma unroll 1
                for (int c = 0; c < CPT; ++c) {
                    int j = c * NT + tid;
                    float4 b0 = xb[j * 2];
                    float4 b1 = xb[j * 2 + 1];
                    float m = dist_m(b0, b1, sqb[j], A, Bv);
                    float d2c = fmaxf(Bv.w + m, 0.f);
                    if (j == iq) continue;
                    bool gt = (d2c > lastv) || (d2c == lastv && j > lasti);
                    if (gt && (d2c < best || (d2c == best && j < bidx))) {
                        best = d2c; bidx = j;
                    }
                }
#pragma unroll
                for (int off = 32; off > 0; off >>= 1) {
                    float ov = __shfl_down(best, off);
                    int   oi = __shfl_down(bidx, off);
                    if (ov < best || (ov == best && oi < bidx)) { best = ov; bidx = oi; }
                }
                if (lane == 0) { redv[wave] = best; redi[wave] = bidx; }
                __syncthreads();
                if (tid == 0) {
                    float bv = redv[0]; int bi = redi[0];
#pragma unroll
                    for (int w = 1; w < 8; ++w)
                        if (redv[w] < bv || (redv[w] == bv && redi[w] < bi)) {
                            bv = redv[w]; bi = redi[w];
                        }
                    bcv = bv; bci = bi;
                    nbr[q][it] = bi;
                }
                __syncthreads();
                lastv = bcv; lasti = bci;
            }
        }
    }
    __syncthreads();

    // ---- attention epilogue: wave w -> query w, lanes 0..31 ----
    {
        const int q  = wave;
        const int iq = i0 + q;
        if (lane < K) {
            int nk = nbr[q][lane];
            float s = 0.f;
#pragma unroll
            for (int c = 0; c < D; ++c) s += outb[iq * D + c] * aw[c];
            float xp[D + 1];
#pragma unroll
            for (int c = 0; c < D; ++c) {
                float on = outb[nk * D + c];
                xp[c] = on;
                s += on * aw[D + c];
            }
            xp[D] = x[nk * 8 + 7];

            float m = s;
#pragma unroll
            for (int off = 16; off > 0; off >>= 1) m = fmaxf(m, __shfl_xor(m, off, 32));
            float e = expf(s - m);
            float sum = e;
#pragma unroll
            for (int off = 16; off > 0; off >>= 1) sum += __shfl_xor(sum, off, 32);
            float att = e / sum;

            float agg[D + 1];
#pragma unroll
            for (int dd = 0; dd < D + 1; ++dd) {
                float v = att * xp[dd];
#pragma unroll
                for (int off = 16; off > 0; off >>= 1) v += __shfl_xor(v, off, 32);
                agg[dd] = v;
            }

            if (lane < D) {
                float o = outb[iq * D + lane];
                dout[iq * 15 + lane] = o;
                dout[N_NODES * 15 + iq * 15 + lane] = o;
            }
            if (lane < D + 1) {
                float av_ = agg[0];
#pragma unroll
                for (int dd = 1; dd < D + 1; ++dd) av_ = (lane == dd) ? agg[dd] : av_;
                dout[iq * 15 + D + lane] = av_;
                dout[N_NODES * 15 + iq * 15 + D + lane] = av_;
            }
            if (iq == N_NODES - 1) dout[2 * N_NODES * 15 + lane] = att;
        }
    }
}

extern "C" void kernel_launch(void* const* d_in, const int* in_sizes, int n_in,
                              void* d_out, int out_size, void* d_ws, size_t ws_size,
                              hipStream_t stream) {
    (void)in_sizes; (void)n_in; (void)out_size; (void)ws_size;
    const float* x = (const float*)d_in[0];
    const float* W = (const float*)d_in[1];
    const float* a = (const float*)d_in[2];
    float* out  = (float*)d_out;
    float* outb = (float*)d_ws;                       // 8192*7 f32
    float* sqb  = outb + N_NODES * D;                 // 8192 f32
    uint4* fh   = (uint4*)(sqb + N_NODES);            // 8192 * 16 B (16B-aligned)

    hipLaunchKernelGGL(precompute_kernel, dim3(N_NODES / 256), dim3(256),
                       0, stream, x, W, outb, sqb, fh);
    hipLaunchKernelGGL(gat_kernel, dim3(N_NODES / QB), dim3(NT),
                       0, stream, x, a, outb, sqb, fh, out);
}